// Round 9
// baseline (188.444 us; speedup 1.0000x reference)
//
#include <hip/hip_runtime.h>

#define BS 32
#define NA 512
#define ID 128
#define NH 8
#define HD 64
#define NHD 512   // NH*HD
#define NEG 0.2f

// K1: h_prime = h @ W (fp32). Block = 16 rows x 512 cols, 4 waves: wave w has
// rows (w>>1)*8..+7 (wave-uniform -> A via s_load, zero LDS) and cols
// (w&1)*256 + 4*lane (dense 1KB W loads). Proven R7.
__global__ __launch_bounds__(256) void k1_gemm(
    const float* __restrict__ h, const float* __restrict__ W,
    const float* __restrict__ att, float* __restrict__ hp,
    float* __restrict__ s_out, float* __restrict__ t_out) {
  int blk = blockIdx.x;
  int b = blk >> 5;
  int n0 = (blk & 31) * 16;
  int t = threadIdx.x;
  int lane = t & 63, w = t >> 6;
  int r0 = __builtin_amdgcn_readfirstlane((w >> 1) * 8);   // 0 or 8
  int chalf = __builtin_amdgcn_readfirstlane(w & 1);
  int col = chalf * 256 + lane * 4;
  int head = col >> 6;
  int d0 = col & 63;
  const float* arow = h + ((size_t)b * NA + n0 + r0) * ID;  // uniform base
  const float* wptr = W + col;

  float4 a0c = {0,0,0,0}, a1c = {0,0,0,0}, a2c = {0,0,0,0}, a3c = {0,0,0,0};
  float4 a4c = {0,0,0,0}, a5c = {0,0,0,0}, a6c = {0,0,0,0}, a7c = {0,0,0,0};

#define K1_ROW(I, C, KK)                                                      \
  { float a_ = arow[(I) * ID + kc + (KK)];                                    \
    C.x += a_ * wv.x; C.y += a_ * wv.y; C.z += a_ * wv.z; C.w += a_ * wv.w; }
  #pragma unroll 1
  for (int kc = 0; kc < ID; kc += 8) {
    #pragma unroll
    for (int kk = 0; kk < 8; ++kk) {
      float4 wv = *(const float4*)(wptr + (size_t)(kc + kk) * NHD);
      K1_ROW(0, a0c, kk) K1_ROW(1, a1c, kk) K1_ROW(2, a2c, kk)
      K1_ROW(3, a3c, kk) K1_ROW(4, a4c, kk) K1_ROW(5, a5c, kk)
      K1_ROW(6, a6c, kk) K1_ROW(7, a7c, kk)
    }
  }
#undef K1_ROW
  {
    size_t off = ((((size_t)b * NH + head) * NA) + (n0 + r0)) * HD + d0;
    *(float4*)(hp + off) = a0c; off += HD;
    *(float4*)(hp + off) = a1c; off += HD;
    *(float4*)(hp + off) = a2c; off += HD;
    *(float4*)(hp + off) = a3c; off += HD;
    *(float4*)(hp + off) = a4c; off += HD;
    *(float4*)(hp + off) = a5c; off += HD;
    *(float4*)(hp + off) = a6c; off += HD;
    *(float4*)(hp + off) = a7c;
  }
  {
    float4 as4 = *(const float4*)(att + head * 128 + d0);
    float4 ad4 = *(const float4*)(att + head * 128 + 64 + d0);
#define DOT4(C, A) ((C).x*(A).x + (C).y*(A).y + (C).z*(A).z + (C).w*(A).w)
    float sp0 = DOT4(a0c, as4), tp0 = DOT4(a0c, ad4);
    float sp1 = DOT4(a1c, as4), tp1 = DOT4(a1c, ad4);
    float sp2 = DOT4(a2c, as4), tp2 = DOT4(a2c, ad4);
    float sp3 = DOT4(a3c, as4), tp3 = DOT4(a3c, ad4);
    float sp4 = DOT4(a4c, as4), tp4 = DOT4(a4c, ad4);
    float sp5 = DOT4(a5c, as4), tp5 = DOT4(a5c, ad4);
    float sp6 = DOT4(a6c, as4), tp6 = DOT4(a6c, ad4);
    float sp7 = DOT4(a7c, as4), tp7 = DOT4(a7c, ad4);
#undef DOT4
    #pragma unroll
    for (int m = 1; m < 16; m <<= 1) {
      sp0 += __shfl_xor(sp0, m, 64); tp0 += __shfl_xor(tp0, m, 64);
      sp1 += __shfl_xor(sp1, m, 64); tp1 += __shfl_xor(tp1, m, 64);
      sp2 += __shfl_xor(sp2, m, 64); tp2 += __shfl_xor(tp2, m, 64);
      sp3 += __shfl_xor(sp3, m, 64); tp3 += __shfl_xor(tp3, m, 64);
      sp4 += __shfl_xor(sp4, m, 64); tp4 += __shfl_xor(tp4, m, 64);
      sp5 += __shfl_xor(sp5, m, 64); tp5 += __shfl_xor(tp5, m, 64);
      sp6 += __shfl_xor(sp6, m, 64); tp6 += __shfl_xor(tp6, m, 64);
      sp7 += __shfl_xor(sp7, m, 64); tp7 += __shfl_xor(tp7, m, 64);
    }
    int g16 = lane & 15;
    int rsel = g16 & 7;
    float sv_ = rsel == 0 ? sp0 : rsel == 1 ? sp1 : rsel == 2 ? sp2 :
                rsel == 3 ? sp3 : rsel == 4 ? sp4 : rsel == 5 ? sp5 :
                rsel == 6 ? sp6 : sp7;
    float tv_ = rsel == 0 ? tp0 : rsel == 1 ? tp1 : rsel == 2 ? tp2 :
                rsel == 3 ? tp3 : rsel == 4 ? tp4 : rsel == 5 ? tp5 :
                rsel == 6 ? tp6 : tp7;
    size_t off = (((size_t)b * NH + head) * NA) + n0 + r0 + rsel;
    if (g16 < 8) s_out[off] = sv_;
    else         t_out[off] = tv_;
  }
}

// K2: whole (b,h) problem in LDS. Vp[j][d] = wp[j]*V[tpm[j]][d] staged once
// (only global read); chunked prefix tables; emission is fixed-trip LDS-only
// loops with coalesced output stores. 160,808 B static LDS (< 160 KiB cap).
__global__ __launch_bounds__(512) void k2_lds(
    const float* __restrict__ hp, const float* __restrict__ s_g,
    const float* __restrict__ t_g, float* __restrict__ out) {
  __shared__ float Vp[NA * HD];          // 131072 B, weighted permuted V
  __shared__ float tvs[NA];              // sorted t values
  __shared__ int   tpm[NA];              // sorted-pos -> original row
  __shared__ float rr[NA];               // e^{-0.8 t} (wn = rr * wp)
  __shared__ float preP[33 * 64];        // chunk prefix of Vp sums
  __shared__ float preN[33 * 64];        // chunk prefix of rr*Vp sums
  __shared__ float totP[64];
  __shared__ float svx[NA];              // s value per original row
  __shared__ float aI[NA];               // 1/den per original row
  __shared__ int   aJ[NA];               // js per original row
  __shared__ float szPs[33];             // scalar suffix sums of wp (chunk)
  __shared__ float szNp[33];             // scalar prefix sums of wn (chunk)
  __shared__ float smax8[8];

  int bh = blockIdx.x;
  int t = threadIdx.x;
  int lane = t & 63, w = t >> 6;
  const float* vbase = hp + (size_t)bh * NA * HD;

  // hybrid bitonic sort of t ascending (regs + shfl <64, LDS >=64). Proven R7.
  float tvr = t_g[(size_t)bh * NA + t];
  int tir = t;
  for (int size = 2; size <= NA; size <<= 1) {
    bool dirAsc = ((t & size) == 0);
    for (int stride = size >> 1; stride > 0; stride >>= 1) {
      float pv; int pi;
      if (stride >= 64) {
        tvs[t] = tvr; tpm[t] = tir;
        __syncthreads();
        pv = tvs[t ^ stride]; pi = tpm[t ^ stride];
        __syncthreads();
      } else {
        pv = __shfl_xor(tvr, stride, 64);
        pi = __shfl_xor(tir, stride, 64);
      }
      bool mn = (((t & stride) == 0) == dirAsc);
      bool sw = mn ? (pv < tvr) : (pv > tvr);
      if (sw) { tvr = pv; tir = pi; }
    }
  }
  tvs[t] = tvr; tpm[t] = tir;
  rr[t] = __expf(-0.8f * tvr);
  float sval = s_g[(size_t)bh * NA + t];
  svx[t] = sval;
  {
    float m = sval;
    #pragma unroll
    for (int d = 32; d; d >>= 1) m = fmaxf(m, __shfl_xor(m, d, 64));
    if (lane == 0) smax8[w] = m;
  }
  __syncthreads();

  float cmax = fmaxf(tvs[NA - 1], 0.f);
  float amax = fmaxf(fmaxf(fmaxf(smax8[0], smax8[1]), fmaxf(smax8[2], smax8[3])),
                     fmaxf(fmaxf(smax8[4], smax8[5]), fmaxf(smax8[6], smax8[7])));
  amax = fmaxf(amax, 0.f);

  // stage Vp = wp * permuted V (the only global read of hp)
  #pragma unroll 4
  for (int i = 0; i < 64; ++i) {
    int j = w * 64 + i;
    int src = tpm[j];
    float wpj = __expf(tvs[j] - cmax);
    Vp[j * HD + lane] = wpj * vbase[(size_t)src * HD + lane];
  }
  __syncthreads();

  // chunk vector sums (raw) into preP/preN slots [cc*64+lane]
  for (int cc = w; cc < 32; cc += 8) {
    float aP = 0.f, aN = 0.f;
    #pragma unroll
    for (int jj = 0; jj < 16; ++jj) {
      int j = cc * 16 + jj;
      float v = Vp[j * HD + lane];
      aP += v;
      aN += rr[j] * v;
    }
    preP[cc * 64 + lane] = aP;
    preN[cc * 64 + lane] = aN;
  }
  // scalar chunk sums of wp / wn
  if (t < 32) {
    float a = 0.f;
    for (int j = t * 16; j < t * 16 + 16; ++j) a += __expf(tvs[j] - cmax);
    szPs[t] = a;
  } else if (t < 64) {
    int c = t - 32; float a = 0.f;
    for (int j = c * 16; j < c * 16 + 16; ++j) a += __expf(NEG * tvs[j] - cmax);
    szNp[c] = a;
  }
  __syncthreads();

  // scans: scalar (t=0,1) + vector chunk prefix (t in [64,192))
  if (t == 0) {
    float run = 0.f;
    szPs[32] = 0.f;
    for (int cc = 31; cc >= 0; --cc) { float o = szPs[cc]; szPs[cc] = run + o; run += o; }
    // convert to suffix-from-chunk: szPs[cc] = sum_{k>=cc*16} wp  (done above)
  } else if (t == 1) {
    float run = 0.f;
    for (int cc = 0; cc < 32; ++cc) { float o = szNp[cc]; szNp[cc] = run; run += o; }
    szNp[32] = run;
  } else if (t >= 64 && t < 128) {
    int d = t - 64; float run = 0.f;
    for (int cc = 0; cc < 32; ++cc) {
      float o = preP[cc * 64 + d]; preP[cc * 64 + d] = run; run += o;
    }
    preP[32 * 64 + d] = run;
    totP[d] = run;
  } else if (t >= 128 && t < 192) {
    int d = t - 128; float run = 0.f;
    for (int cc = 0; cc < 32; ++cc) {
      float o = preN[cc * 64 + d]; preN[cc * 64 + d] = run; run += o;
    }
    preN[32 * 64 + d] = run;
  }
  __syncthreads();

  // per original row: js + exact 1/den
  {
    float A = __expf(sval - amax);
    float B = __expf(NEG * sval - amax);
    float key = -sval;
    int lo = 0, hi = NA;
    while (lo < hi) { int mid = (lo + hi) >> 1; if (tvs[mid] < key) lo = mid + 1; else hi = mid; }
    int js = lo;
    float zps, znp;
    if (js == NA) {
      zps = 0.f; znp = szNp[32];
    } else {
      int ch = js >> 4;
      zps = szPs[ch + 1];
      for (int k = js; k < ch * 16 + 16; ++k) zps += __expf(tvs[k] - cmax);
      znp = szNp[ch];
      for (int k = ch * 16; k < js; ++k) znp += __expf(NEG * tvs[k] - cmax);
    }
    aI[t] = 1.f / (A * zps + B * znp);
    aJ[t] = js;
  }
  __syncthreads();

  // emission: wave w -> original rows [w*64, w*64+64). All LDS + coalesced out.
  {
    for (int i = 0; i < 64; ++i) {
      int row = w * 64 + i;
      int js = aJ[row];
      float inv = aI[row];
      float s = svx[row];
      float A = __expf(s - amax);
      float B = __expf(NEG * s - amax);
      int cs = js >> 4; if (cs > 31) cs = 31;
      float pos = totP[lane] - preP[(cs + 1) * 64 + lane];
      float neg = preN[cs * 64 + lane];
      #pragma unroll
      for (int jj = 0; jj < 16; ++jj) {
        int j = cs * 16 + jj;
        float v = Vp[j * HD + lane];
        if (j >= js) pos += v;
        else         neg += rr[j] * v;
      }
      float x = (A * pos + B * neg) * inv;
      out[((size_t)bh * NA + row) * HD + lane] = x > 0.f ? x : __expf(x) - 1.f;
    }
  }
}

extern "C" void kernel_launch(void* const* d_in, const int* in_sizes, int n_in,
                              void* d_out, int out_size, void* d_ws, size_t ws_size,
                              hipStream_t stream) {
  const float* h  = (const float*)d_in[0];
  const float* W  = (const float*)d_in[1];
  const float* att = (const float*)d_in[2];
  float* out = (float*)d_out;
  // ws: hp 33.5MB | s 0.5MB | t 0.5MB
  float* hp    = (float*)d_ws;
  float* s_arr = hp + (size_t)BS * NH * NA * HD;
  float* t_arr = s_arr + (size_t)BS * NH * NA;

  k1_gemm<<<dim3(1024), dim3(256), 0, stream>>>(h, W, att, hp, s_arr, t_arr);
  k2_lds <<<dim3(256),  dim3(512), 0, stream>>>(hp, s_arr, t_arr, out);
}